// Round 14
// baseline (465.748 us; speedup 1.0000x reference)
//
#include <hip/hip_runtime.h>
#include <math.h>

#define NN_ 32768      // nodes
#define NE_ 49152      // edges
#define NG_ 1024       // graphs

typedef short bh8 __attribute__((ext_vector_type(8)));   // 8 bf16 bit-patterns (4 VGPR)
typedef float f32x4 __attribute__((ext_vector_type(4)));

__device__ __forceinline__ unsigned short f2bfu(float f) {   // RNE float->bf16 bits
    union { float f; unsigned int i; } x; x.f = f;
    unsigned int u = x.i;
    u += 0x7FFFu + ((u >> 16) & 1u);
    return (unsigned short)(u >> 16);
}
__device__ __forceinline__ float sigm(float x) { return 1.f / (1.f + expf(-x)); }

// Kept for harness compatibility (unused).
__global__ void MPNN_78632261256134_kernel() {}

// ---------------- fused init zero: deg (int) | agg ----------------
__global__ void k_init(int* deg, float* agg) {
    int i = blockIdx.x * 256 + threadIdx.x;
    if (i < NN_) deg[i] = 0;
    int k = i - NN_;
    if (k >= 0 && k < NN_ * 64) agg[k] = 0.f;
}

// ---------------- lin0 ----------------
__global__ void k_lin0(const float* x, const float* W, const float* b, float* node) {
    int g = blockIdx.x * 256 + threadIdx.x;   // n*64+d
    int n = g >> 6, d = g & 63;
    const float* xr = x + n * 14;
    const float* wr = W + d * 14;
    float acc = b[d];
    for (int i = 0; i < 14; i++) acc += xr[i] * wr[i];
    node[g] = fmaxf(acc, 0.f);
}

// ---------------- in-degree count (int) ----------------
__global__ void k_cnt(const int* dst, int* deg) {
    int e = blockIdx.x * 256 + threadIdx.x;
    if (e < NE_) atomicAdd(&deg[dst[e]], 1);
}

// ---------------- two-phase parallel prefix scan ----------------
__global__ __launch_bounds__(256) void k_scanA(const int* __restrict__ deg,
                                               int* __restrict__ offs,
                                               int* __restrict__ bsum) {
    __shared__ int wtot[4];
    int tid = threadIdx.x, bid = blockIdx.x;
    int i = bid * 256 + tid;
    int v = deg[i];
    int sc = v;
    for (int o = 1; o < 64; o <<= 1) { int u = __shfl_up(sc, o); if ((tid & 63) >= o) sc += u; }
    if ((tid & 63) == 63) wtot[tid >> 6] = sc;
    __syncthreads();
    int wpre = 0;
    for (int k = 0; k < (tid >> 6); k++) wpre += wtot[k];
    offs[i] = sc + wpre - v;              // exclusive within block
    if (tid == 255) bsum[bid] = sc + wpre; // block total
}

__global__ __launch_bounds__(256) void k_scanC(const int* __restrict__ bsum,
                                               int* __restrict__ offs,
                                               int* __restrict__ head) {
    __shared__ int boff;
    int tid = threadIdx.x, bid = blockIdx.x;
    if (tid == 0) {
        int s = 0;
        for (int k = 0; k < bid; k++) s += bsum[k];
        boff = s;
    }
    __syncthreads();
    int i = bid * 256 + tid;
    int o = offs[i] + boff;
    offs[i] = o; head[i] = o;
    if (i == NN_ - 1) offs[NN_] = NE_;
}

// ---------------- scatter: perm = edges sorted by dst (counting sort) ----------------
__global__ void k_scatter(const int* __restrict__ dst, int* __restrict__ head,
                          int* __restrict__ perm) {
    int e = blockIdx.x * 256 + threadIdx.x;
    if (e < NE_) { int p = atomicAdd(&head[dst[e]], 1); perm[p] = e; }
}

// ---------------- graph segment bounds for Set2Set ----------------
__global__ void k_gbnd(const int* __restrict__ batch, int* __restrict__ gb) {
    int n = blockIdx.x * 256 + threadIdx.x;
    if (n >= NN_) return;
    int b = batch[n];
    if (n == 0) { for (int g = 0; g <= b; g++) gb[g] = 0; }
    else {
        int pb = batch[n - 1];
        for (int g = pb + 1; g <= b; g++) gb[g] = n;
    }
    if (n == NN_ - 1) { for (int g = b + 1; g <= NG_; g++) gb[g] = NN_; }
}

// ---------------- fused weight transposes (+ fc1W transpose for coalesced k_fc) ----------
__global__ void k_tw(const float* gWih, const float* gWhh, float* WihT, float* WhhT,
                     const float* lWih, const float* lWhh, float* WihT2, float* WhhT2,
                     const float* fc1W, float* fc1WT) {
    int t = blockIdx.x * 256 + threadIdx.x;
    if (t < 12288) {
        int gr = t >> 6, i = t & 63; WihT[i * 192 + gr] = gWih[t];
    } else if (t < 24576) {
        int u = t - 12288; int gr = u >> 6, i = u & 63; WhhT[i * 192 + gr] = gWhh[u];
    } else if (t < 57344) {
        int u = t - 24576; int r = u >> 7, c = u & 127; WihT2[c * 256 + r] = lWih[u];
    } else if (t < 73728) {
        int u = t - 57344; int r = u >> 6, c = u & 63; WhhT2[c * 256 + r] = lWhh[u];
    } else if (t < 90112) {
        int u = t - 73728; int r = u >> 7, c = u & 127; fc1WT[c * 128 + r] = fc1W[u];
    }
}

// ---------------- Bhat3: frag-contiguous bf16 B [s][w][t][lane][8] ----------------
__global__ void k_bhat3(const float* e2W, unsigned short* Bhat3) {
    int idx = blockIdx.x * 256 + threadIdx.x;   // < 524288
    if (idx >= 64 * 4 * 4 * 64 * 8) return;
    int j = idx & 7, lane = (idx >> 3) & 63, t = (idx >> 9) & 3, w = (idx >> 11) & 3, s = idx >> 13;
    int row = s * 64 + w * 16 + (lane & 15);
    int k = t * 32 + (lane >> 4) * 8 + j;
    Bhat3[idx] = f2bfu(e2W[row * 128 + k]);
}

// ---------------- Hhat: frag-ready He in dst-sorted edge order ----------------
__global__ __launch_bounds__(256) void k_he(const float* __restrict__ ea,
                                            const float* __restrict__ e1W,
                                            const float* __restrict__ e1b,
                                            const int* __restrict__ perm,
                                            unsigned short* __restrict__ Hhat) {
    int tid = threadIdx.x;
    int lane = tid & 63, sub = tid >> 6;
    int gi = blockIdx.x * 4 + sub;            // < 12288
    int etile = gi >> 2, t = gi & 3;
    int e = etile * 16 + (lane & 15), quad = lane >> 4;
    int eo = perm[e];
    const float* ar = ea + (size_t)eo * 4;
    float a0 = ar[0], a1 = ar[1], a2 = ar[2], a3 = ar[3];
    union { unsigned short u[8]; uint4 q; } o;
#pragma unroll
    for (int j = 0; j < 8; j++) {
        int c = t * 32 + quad * 8 + j;
        const float* wr = e1W + c * 4;
        float h = e1b[c] + a0 * wr[0] + a1 * wr[1] + a2 * wr[2] + a3 * wr[3];
        o.u[j] = f2bfu(fmaxf(h, 0.f));
    }
    *(uint4*)(Hhat + (size_t)gi * 512 + lane * 8) = o.q;
}

// ---------------- MFMA NNConv (round-10 proven): prefetched body + segment-reduce epilogue ----
#define PS(S) (((S) + soff) & 63)

#define LDB(B, S) {                                                                       \
        const unsigned short* _p = Bhat3 + (size_t)PS(S) * 8192 + w * 2048 + lane * 8;    \
        (B)[0] = *(const bh8*)(const void*)(_p);                                          \
        (B)[1] = *(const bh8*)(const void*)(_p + 512);                                    \
        (B)[2] = *(const bh8*)(const void*)(_p + 1024);                                   \
        (B)[3] = *(const bh8*)(const void*)(_p + 1536); }

#define LDXV(XV, S) {                                                                     \
        int sp_ = PS(S);                                                                  \
        _Pragma("unroll")                                                                 \
        for (int mt_ = 0; mt_ < 4; mt_++)                                                 \
            (XV)[mt_] = *(const f32x4*)(const void*)(xs + sp_ * 68 + mt_ * 16 + quad * 4); }

#define LDBB(BB, S) (BB) = e2b[PS(S) * 64 + w * 16 + mrow];

#define MFMA16(ACC, B) {                                                                  \
        __builtin_amdgcn_s_setprio(1);                                                    \
        _Pragma("unroll")                                                                 \
        for (int t_ = 0; t_ < 4; t_++) {                                                  \
            _Pragma("unroll")                                                             \
            for (int mt_ = 0; mt_ < 4; mt_++)                                             \
                (ACC)[mt_] = __builtin_amdgcn_mfma_f32_16x16x32_bf16(                     \
                    af[mt_][t_], (B)[t_], (t_ == 0) ? z4 : (ACC)[mt_], 0, 0, 0);          \
        }                                                                                 \
        __builtin_amdgcn_s_setprio(0); }

#define CONSUME(ACC, XV, BB) {                                                            \
        _Pragma("unroll")                                                                 \
        for (int mt_ = 0; mt_ < 4; mt_++) {                                               \
            _Pragma("unroll")                                                             \
            for (int r_ = 0; r_ < 4; r_++)                                                \
                msgv[mt_][r_] += (XV)[mt_][r_] * ((ACC)[mt_][r_] + (BB));                 \
        } }

__global__ __launch_bounds__(256, 2) void k_convr(const float* __restrict__ node,
                                                  const unsigned short* __restrict__ Hhat,
                                                  const unsigned short* __restrict__ Bhat3,
                                                  const float* __restrict__ e2b,
                                                  const int* __restrict__ src,
                                                  const int* __restrict__ dst,
                                                  const int* __restrict__ perm,
                                                  float* __restrict__ agg) {
    __shared__ __align__(16) float xs[64 * 68];   // xs[s][e]; reused as msT[e][d] in epilogue
    __shared__ int dst_s[64];

    const int tid = threadIdx.x;
    const int eb = blockIdx.x * 64;
    const int lane = tid & 63, w = tid >> 6;
    const int quad = lane >> 4, mrow = lane & 15;
    const int soff = (blockIdx.x * 37) & 63;

    {
        int r = tid >> 2, c = tid & 3;
        int s = src[perm[eb + r]];
        const float* nr = node + (size_t)s * 64 + c * 16;
#pragma unroll
        for (int j = 0; j < 16; j++) xs[(c * 16 + j) * 68 + r] = nr[j];
        if (tid < 64) dst_s[tid] = dst[perm[eb + tid]];
    }

    bh8 af[4][4];
#pragma unroll
    for (int mt = 0; mt < 4; mt++)
#pragma unroll
        for (int t = 0; t < 4; t++)
            af[mt][t] = *(const bh8*)(const void*)(
                Hhat + (size_t)(((eb >> 4) + mt) * 4 + t) * 512 + lane * 8);
    __syncthreads();

    const f32x4 z4 = {0.f, 0.f, 0.f, 0.f};
    f32x4 msgv[4];
#pragma unroll
    for (int mt = 0; mt < 4; mt++) msgv[mt] = z4;

    bh8 b0[4], b1[4];
    f32x4 xvA[4], xvB[4];
    f32x4 accA[4], accB[4];
    float bbA, bbB;

    // prologue: accA = W(0) issued, b1 = B(1), b0 = B(2), xvA = x(0), bbA = bb(0)
    LDB(b0, 0)
    LDB(b1, 1)
    LDXV(xvA, 0)
    LDBB(bbA, 0)
    MFMA16(accA, b0)
    LDB(b0, 2)

#pragma unroll 1
    for (int s = 0; s < 62; s += 2) {
        MFMA16(accB, b1)          // W(s+1)
        LDB(b1, s + 3)
        LDXV(xvB, s + 1)
        LDBB(bbB, s + 1)
        CONSUME(accA, xvA, bbA)   // consume s
        MFMA16(accA, b0)          // W(s+2)
        LDB(b0, (s + 4) & 63)
        LDXV(xvA, s + 2)
        LDBB(bbA, s + 2)
        CONSUME(accB, xvB, bbB)   // consume s+1
    }
    MFMA16(accB, b1)              // W(63)
    CONSUME(accA, xvA, bbA)       // s = 62
    LDXV(xvB, 63)
    LDBB(bbB, 63)
    CONSUME(accB, xvB, bbB)       // s = 63

    // ---- epilogue: transpose msgv via xs, per-window segment reduce ----
    __syncthreads();   // all waves done reading xs
#pragma unroll
    for (int mt = 0; mt < 4; mt++)
#pragma unroll
        for (int r = 0; r < 4; r++)
            xs[(mt * 16 + quad * 4 + r) * 68 + w * 16 + mrow] = msgv[mt][r];
    __syncthreads();
    {
        const int ebase = w * 16;     // this wave's 16-edge window
        const int d = lane;
        float acc = 0.f;
        int startE = ebase;
        int curn = dst_s[ebase];
#pragma unroll
        for (int e = ebase; e < ebase + 16; e++) {
            acc += xs[e * 68 + d];
            int nxt = (e < ebase + 15) ? dst_s[e + 1] : -1;
            if (nxt != curn) {
                float* dp = agg + (size_t)curn * 64 + d;
                if (startE == ebase || e == ebase + 15) atomicAdd(dp, acc);
                else *dp = acc;
                acc = 0.f; startE = e + 1; curn = nxt;
            }
        }
    }
}

// ---------------- fused m+GRU: 512 threads, LDS-staged double-buffered GRU weights ----------
// 64 nodes/block, 8 nodes/thread, 8 waves. GRU weight rows staged into LDS in chunks of 8
// (wave k stages row k: 6 coalesced 256B loads, issued a full chunk ahead) -> per-iteration
// weight reads are conflict-free LDS hits; L2 latency hidden. 16 waves/CU TLP.
__global__ __launch_bounds__(512) void k_mgru(float* __restrict__ agg,
                                              const int* __restrict__ offs,
                                              const float* __restrict__ node,
                                              const float* __restrict__ rootW,
                                              const float* __restrict__ convb,
                                              const float* __restrict__ WihT,
                                              const float* __restrict__ WhhT,
                                              const float* __restrict__ bih,
                                              const float* __restrict__ bhh,
                                              float* __restrict__ hOut) {
    __shared__ __align__(16) float hsT[64][68];   // hsT[i][node]
    __shared__ __align__(16) float msT[64][68];
    __shared__ __align__(16) float ws[2][8][384]; // [buf][row-in-chunk][Wih 0..191 | Whh 192..383]
    const int tid = threadIdx.x;
    const int d = tid & 63, sub = tid >> 6;       // sub in [0,8)
    const int nb = blockIdx.x * 64;
    const int r0 = sub * 8;

    {   // stage h transposed: 8 nodes/thread
#pragma unroll
        for (int j4 = 0; j4 < 2; j4++) {
            f32x4 hv;
#pragma unroll
            for (int j = 0; j < 4; j++)
                hv[j] = node[(size_t)(nb + r0 + j4 * 4 + j) * 64 + d];
            *(f32x4*)&hsT[d][r0 + j4 * 4] = hv;
        }
    }
    __syncthreads();

    // stage GRU weight chunk 0 early (hidden under the m-phase)
    {
        const float* wi = WihT + (size_t)sub * 192;
        const float* wh = WhhT + (size_t)sub * 192;
#pragma unroll
        for (int j = 0; j < 3; j++) {
            ws[0][sub][d + 64 * j] = wi[d + 64 * j];
            ws[0][sub][192 + d + 64 * j] = wh[d + 64 * j];
        }
    }

    {   // m = relu(agg/deg + h@rootW + convb); zero agg; rootW prefetch-1
        float root[8];
#pragma unroll
        for (int j = 0; j < 8; j++) root[j] = 0.f;
        float wv = rootW[d];   // i = 0
        for (int i = 0; i < 64; i++) {
            float wn = rootW[((i + 1) & 63) * 64 + d];   // wraps, always valid
            f32x4 h4a = *(const f32x4*)&hsT[i][r0];
            f32x4 h4b = *(const f32x4*)&hsT[i][r0 + 4];
#pragma unroll
            for (int j = 0; j < 4; j++) { root[j] += h4a[j] * wv; root[4 + j] += h4b[j] * wv; }
            wv = wn;
        }
        float cb = convb[d];
#pragma unroll
        for (int j4 = 0; j4 < 2; j4++) {
            f32x4 mval;
#pragma unroll
            for (int j = 0; j < 4; j++) {
                int n = nb + r0 + j4 * 4 + j;
                float dg = (float)(offs[n + 1] - offs[n]);
                float inv = 1.f / fmaxf(dg, 1.f);
                float av = agg[(size_t)n * 64 + d];
                agg[(size_t)n * 64 + d] = 0.f;
                mval[j] = fmaxf(av * inv + cb + root[j4 * 4 + j], 0.f);
            }
            *(f32x4*)&msT[d][r0 + j4 * 4] = mval;
        }
    }
    __syncthreads();   // msT ready AND ws[0] ready

    float ir[8], iz[8], in_[8], hr[8], hz[8], hn[8];
    {
        float bi0 = bih[d], bi1 = bih[64 + d], bi2 = bih[128 + d];
        float bh0 = bhh[d], bh1 = bhh[64 + d], bh2 = bhh[128 + d];
#pragma unroll
        for (int j = 0; j < 8; j++) {
            ir[j] = bi0; iz[j] = bi1; in_[j] = bi2;
            hr[j] = bh0; hz[j] = bh1; hn[j] = bh2;
        }
    }

#pragma unroll 1
    for (int c = 0; c < 8; c++) {
        int buf = c & 1;
        if (c < 7) {   // stage next chunk into the other buffer
            int i = (c + 1) * 8 + sub;
            const float* wi = WihT + (size_t)i * 192;
            const float* wh = WhhT + (size_t)i * 192;
#pragma unroll
            for (int j = 0; j < 3; j++) {
                ws[buf ^ 1][sub][d + 64 * j] = wi[d + 64 * j];
                ws[buf ^ 1][sub][192 + d + 64 * j] = wh[d + 64 * j];
            }
        }
#pragma unroll
        for (int k = 0; k < 8; k++) {
            int i = c * 8 + k;
            float wi0 = ws[buf][k][d];
            float wi1 = ws[buf][k][64 + d];
            float wi2 = ws[buf][k][128 + d];
            float wh0 = ws[buf][k][192 + d];
            float wh1 = ws[buf][k][256 + d];
            float wh2 = ws[buf][k][320 + d];
            f32x4 m4a = *(const f32x4*)&msT[i][r0];
            f32x4 m4b = *(const f32x4*)&msT[i][r0 + 4];
            f32x4 h4a = *(const f32x4*)&hsT[i][r0];
            f32x4 h4b = *(const f32x4*)&hsT[i][r0 + 4];
#pragma unroll
            for (int j = 0; j < 4; j++) {
                ir[j] += m4a[j] * wi0; iz[j] += m4a[j] * wi1; in_[j] += m4a[j] * wi2;
                hr[j] += h4a[j] * wh0; hz[j] += h4a[j] * wh1; hn[j] += h4a[j] * wh2;
                ir[4 + j] += m4b[j] * wi0; iz[4 + j] += m4b[j] * wi1; in_[4 + j] += m4b[j] * wi2;
                hr[4 + j] += h4b[j] * wh0; hz[4 + j] += h4b[j] * wh1; hn[4 + j] += h4b[j] * wh2;
            }
        }
        __syncthreads();   // protect ws[buf] (re-staged at c+2) and ws[buf^1] (read at c+1)
    }

#pragma unroll
    for (int j = 0; j < 8; j++) {
        float hold = hsT[d][r0 + j];
        float r = sigm(ir[j] + hr[j]);
        float z = sigm(iz[j] + hz[j]);
        float nn = tanhf(in_[j] + r * hn[j]);
        hOut[(size_t)(nb + r0 + j) * 64 + d] = (1.f - z) * nn + z * hold;
    }
}

// ---------------- fused Set2Set x3: state in LDS, two-pass parallel softmax readout ----------
__global__ __launch_bounds__(256) void k_s2s3(const float* __restrict__ node,
                                              const int* __restrict__ gb,
                                              const float* __restrict__ WihT2,
                                              const float* __restrict__ WhhT2,
                                              const float* __restrict__ bih,
                                              const float* __restrict__ bhh,
                                              float* __restrict__ qstar) {
    __shared__ float qvs[128];
    __shared__ float hls[64], cls[64], qsh[64];
    __shared__ float accs[4][64];
    __shared__ float es[256];
    __shared__ float red[4][64];
    __shared__ float sred[4];
    const int b = blockIdx.x, tid = threadIdx.x;
    const int lane = tid & 63, wv = tid >> 6;
    const int start = gb[b], end = gb[b + 1];

    if (tid < 128) qvs[tid] = 0.f;
    else if (tid < 192) hls[tid - 128] = 0.f;
    else cls[tid - 192] = 0.f;
    __syncthreads();

    for (int step = 0; step < 3; step++) {
        // LSTM gates: wave wv computes gate wv for all 64 dims
        float acc = bih[wv * 64 + lane] + bhh[wv * 64 + lane];
        if (step > 0) {
            const float* wih = WihT2 + wv * 64 + lane;
            const float* whh = WhhT2 + wv * 64 + lane;
#pragma unroll 4
            for (int j = 0; j < 128; j++) acc += qvs[j] * wih[(size_t)j * 256];
#pragma unroll 4
            for (int j = 0; j < 64; j++) acc += hls[j] * whh[(size_t)j * 256];
        }
        accs[wv][lane] = acc;
        __syncthreads();
        if (tid < 64) {
            float c = sigm(accs[1][tid]) * cls[tid] + sigm(accs[0][tid]) * tanhf(accs[2][tid]);
            cls[tid] = c;
            float q = sigm(accs[3][tid]) * tanhf(c);
            hls[tid] = q; qsh[tid] = q;
        }
        __syncthreads();
        const float q = qsh[lane];

        float m_run = -1e30f, l_run = 0.f, r_part = 0.f;
        for (int cbase = start; cbase < end; cbase += 256) {
            int cn = min(256, end - cbase);
            // pass A: scores (parallel across 4 waves)
            for (int i = wv; i < cn; i += 4) {
                float nv = node[(size_t)(cbase + i) * 64 + lane];
                float p = nv * q;
#pragma unroll
                for (int o = 32; o > 0; o >>= 1) p += __shfl_xor(p, o);
                if (lane == 0) es[i] = p;
            }
            __syncthreads();
            // pass B: chunk max (block reduce)
            float mloc = -1e30f;
            for (int i = tid; i < cn; i += 256) mloc = fmaxf(mloc, es[i]);
#pragma unroll
            for (int o = 32; o > 0; o >>= 1) mloc = fmaxf(mloc, __shfl_xor(mloc, o));
            if (lane == 0) sred[wv] = mloc;
            __syncthreads();
            float m_chunk = fmaxf(fmaxf(sred[0], sred[1]), fmaxf(sred[2], sred[3]));
            float m_new = fmaxf(m_run, m_chunk);
            float sc = expf(m_run - m_new);
            // pass L: weights + chunk sum
            float lloc = 0.f;
            for (int i = tid; i < cn; i += 256) {
                float wgt = expf(es[i] - m_new);
                es[i] = wgt; lloc += wgt;
            }
#pragma unroll
            for (int o = 32; o > 0; o >>= 1) lloc += __shfl_xor(lloc, o);
            __syncthreads();
            if (lane == 0) sred[wv] = lloc;
            __syncthreads();
            float l_chunk = sred[0] + sred[1] + sred[2] + sred[3];
            l_run = l_run * sc + l_chunk;
            // pass C: weighted node-row sum
            r_part *= sc;
            for (int i = wv; i < cn; i += 4)
                r_part += es[i] * node[(size_t)(cbase + i) * 64 + lane];
            m_run = m_new;
            __syncthreads();   // es reused next chunk
        }
        red[wv][lane] = r_part;
        __syncthreads();
        if (tid < 64) {
            float r = red[0][tid] + red[1][tid] + red[2][tid] + red[3][tid];
            qvs[tid] = qsh[tid];
            qvs[64 + tid] = (end > start) ? r / l_run : 0.f;
        }
        __syncthreads();
    }
    if (tid < 128) qstar[(size_t)b * 128 + tid] = qvs[tid];
}

// ---------------- head (coalesced via transposed fc1W) ----------------
__global__ void k_fc(const float* qstar, const float* W1T, const float* b1,
                     const float* W2, const float* b2, float* out) {
    __shared__ float hid[128];
    __shared__ float qs[128];
    int b = blockIdx.x; int t = threadIdx.x;  // 128 threads
    qs[t] = qstar[(size_t)b * 128 + t];
    __syncthreads();
    float acc = b1[t];
    for (int k = 0; k < 128; k++) acc += qs[k] * W1T[k * 128 + t];
    hid[t] = fmaxf(acc, 0.f);
    __syncthreads();
    if (t < 64) {
        float s = hid[t] * W2[t] + hid[t + 64] * W2[t + 64];
        for (int o = 32; o > 0; o >>= 1) s += __shfl_xor(s, o);
        if (t == 0) out[b] = s + b2[0];
    }
}

extern "C" void kernel_launch(void* const* d_in, const int* in_sizes, int n_in,
                              void* d_out, int out_size, void* d_ws, size_t ws_size,
                              hipStream_t stream) {
    const float* x     = (const float*)d_in[0];
    const int*   ei    = (const int*)d_in[1];
    const float* ea    = (const float*)d_in[2];
    const int*   batch = (const int*)d_in[3];
    const float* lin0W = (const float*)d_in[4];
    const float* lin0b = (const float*)d_in[5];
    const float* e1W   = (const float*)d_in[6];
    const float* e1b   = (const float*)d_in[7];
    const float* e2W   = (const float*)d_in[8];
    const float* e2b   = (const float*)d_in[9];
    const float* rootW = (const float*)d_in[10];
    const float* convb = (const float*)d_in[11];
    const float* gWih  = (const float*)d_in[12];
    const float* gWhh  = (const float*)d_in[13];
    const float* gbih  = (const float*)d_in[14];
    const float* gbhh  = (const float*)d_in[15];
    const float* lWih  = (const float*)d_in[16];
    const float* lWhh  = (const float*)d_in[17];
    const float* lbih  = (const float*)d_in[18];
    const float* lbhh  = (const float*)d_in[19];
    const float* fc1W  = (const float*)d_in[20];
    const float* fc1b  = (const float*)d_in[21];
    const float* fc2W  = (const float*)d_in[22];
    const float* fc2b  = (const float*)d_in[23];
    const int* src = ei;
    const int* dst = ei + NE_;

    // workspace carve (~33 MB)
    char* p = (char*)d_ws;
    auto alloc = [&](size_t bytes) -> char* {
        char* r = p; p += (bytes + 255) & ~(size_t)255; return r;
    };
    unsigned short* Bhat3 = (unsigned short*)alloc((size_t)524288 * 2);        // 1.05 MB
    unsigned short* Hhat  = (unsigned short*)alloc((size_t)NE_ * 128 * 2);     // 12.6 MB
    float* nodeA  = (float*)alloc((size_t)NN_ * 64 * 4);
    float* nodeB  = (float*)alloc((size_t)NN_ * 64 * 4);
    float* aggb   = (float*)alloc((size_t)NN_ * 64 * 4);
    int*   deg    = (int*)alloc((size_t)NN_ * 4);
    int*   offs   = (int*)alloc((size_t)(NN_ + 1) * 4);
    int*   head   = (int*)alloc((size_t)NN_ * 4);
    int*   perm   = (int*)alloc((size_t)NE_ * 4);
    int*   bsum   = (int*)alloc((size_t)128 * 4);
    int*   gb     = (int*)alloc((size_t)(NG_ + 1) * 4);
    float* WihT   = (float*)alloc(192 * 64 * 4);
    float* WhhT   = (float*)alloc(192 * 64 * 4);
    float* WihT2  = (float*)alloc(256 * 128 * 4);
    float* WhhT2  = (float*)alloc(256 * 64 * 4);
    float* fc1WT  = (float*)alloc(128 * 128 * 4);
    float* qstar  = (float*)alloc((size_t)NG_ * 128 * 4);

    k_init<<<(NN_ + NN_ * 64 + 255) / 256, 256, 0, stream>>>(deg, aggb);
    k_lin0<<<NN_ * 64 / 256, 256, 0, stream>>>(x, lin0W, lin0b, nodeA);
    k_cnt<<<NE_ / 256, 256, 0, stream>>>(dst, deg);
    k_scanA<<<NN_ / 256, 256, 0, stream>>>(deg, offs, bsum);
    k_scanC<<<NN_ / 256, 256, 0, stream>>>(bsum, offs, head);
    k_scatter<<<NE_ / 256, 256, 0, stream>>>(dst, head, perm);
    k_gbnd<<<NN_ / 256, 256, 0, stream>>>(batch, gb);
    k_tw<<<352, 256, 0, stream>>>(gWih, gWhh, WihT, WhhT, lWih, lWhh, WihT2, WhhT2,
                                  fc1W, fc1WT);
    k_bhat3<<<524288 / 256, 256, 0, stream>>>(e2W, Bhat3);
    k_he<<<NE_ / 16, 256, 0, stream>>>(ea, e1W, e1b, perm, Hhat);   // sorted edge order

    float* curF = nodeA; float* nxtF = nodeB;
    for (int it = 0; it < 3; it++) {
        k_convr<<<NE_ / 64, 256, 0, stream>>>(curF, Hhat, Bhat3, e2b, src, dst, perm, aggb);
        k_mgru<<<NN_ / 64, 512, 0, stream>>>(aggb, offs, curF, rootW, convb,
                                             WihT, WhhT, gbih, gbhh, nxtF);
        float* tf = curF; curF = nxtF; nxtF = tf;
    }

    k_s2s3<<<NG_, 256, 0, stream>>>(curF, gb, WihT2, WhhT2, lbih, lbhh, qstar);
    k_fc<<<NG_, 128, 0, stream>>>(qstar, fc1WT, fc1b, fc2W, fc2b, (float*)d_out);
}

// Round 15
// 454.613 us; speedup vs baseline: 1.0245x; 1.0245x over previous
//
#include <hip/hip_runtime.h>
#include <math.h>

#define NN_ 32768      // nodes
#define NE_ 49152      // edges
#define NG_ 1024       // graphs

typedef short bh8 __attribute__((ext_vector_type(8)));   // 8 bf16 bit-patterns (4 VGPR)
typedef float f32x4 __attribute__((ext_vector_type(4)));

__device__ __forceinline__ unsigned short f2bfu(float f) {   // RNE float->bf16 bits
    union { float f; unsigned int i; } x; x.f = f;
    unsigned int u = x.i;
    u += 0x7FFFu + ((u >> 16) & 1u);
    return (unsigned short)(u >> 16);
}
__device__ __forceinline__ float sigm(float x) { return 1.f / (1.f + expf(-x)); }

// Kept for harness compatibility (unused).
__global__ void MPNN_78632261256134_kernel() {}

// ---------------- fused init zero: deg (int) | agg ----------------
__global__ void k_init(int* deg, float* agg) {
    int i = blockIdx.x * 256 + threadIdx.x;
    if (i < NN_) deg[i] = 0;
    int k = i - NN_;
    if (k >= 0 && k < NN_ * 64) agg[k] = 0.f;
}

// ---------------- lin0 ----------------
__global__ void k_lin0(const float* x, const float* W, const float* b, float* node) {
    int g = blockIdx.x * 256 + threadIdx.x;   // n*64+d
    int n = g >> 6, d = g & 63;
    const float* xr = x + n * 14;
    const float* wr = W + d * 14;
    float acc = b[d];
    for (int i = 0; i < 14; i++) acc += xr[i] * wr[i];
    node[g] = fmaxf(acc, 0.f);
}

// ---------------- in-degree count (int) ----------------
__global__ void k_cnt(const int* dst, int* deg) {
    int e = blockIdx.x * 256 + threadIdx.x;
    if (e < NE_) atomicAdd(&deg[dst[e]], 1);
}

// ---------------- two-phase parallel prefix scan ----------------
__global__ __launch_bounds__(256) void k_scanA(const int* __restrict__ deg,
                                               int* __restrict__ offs,
                                               int* __restrict__ bsum) {
    __shared__ int wtot[4];
    int tid = threadIdx.x, bid = blockIdx.x;
    int i = bid * 256 + tid;
    int v = deg[i];
    int sc = v;
    for (int o = 1; o < 64; o <<= 1) { int u = __shfl_up(sc, o); if ((tid & 63) >= o) sc += u; }
    if ((tid & 63) == 63) wtot[tid >> 6] = sc;
    __syncthreads();
    int wpre = 0;
    for (int k = 0; k < (tid >> 6); k++) wpre += wtot[k];
    offs[i] = sc + wpre - v;              // exclusive within block
    if (tid == 255) bsum[bid] = sc + wpre; // block total
}

__global__ __launch_bounds__(256) void k_scanC(const int* __restrict__ bsum,
                                               int* __restrict__ offs,
                                               int* __restrict__ head) {
    __shared__ int boff;
    int tid = threadIdx.x, bid = blockIdx.x;
    if (tid == 0) {
        int s = 0;
        for (int k = 0; k < bid; k++) s += bsum[k];
        boff = s;
    }
    __syncthreads();
    int i = bid * 256 + tid;
    int o = offs[i] + boff;
    offs[i] = o; head[i] = o;
    if (i == NN_ - 1) offs[NN_] = NE_;
}

// ---------------- scatter: perm = edges sorted by dst (counting sort) ----------------
__global__ void k_scatter(const int* __restrict__ dst, int* __restrict__ head,
                          int* __restrict__ perm) {
    int e = blockIdx.x * 256 + threadIdx.x;
    if (e < NE_) { int p = atomicAdd(&head[dst[e]], 1); perm[p] = e; }
}

// ---------------- graph segment bounds for Set2Set ----------------
__global__ void k_gbnd(const int* __restrict__ batch, int* __restrict__ gb) {
    int n = blockIdx.x * 256 + threadIdx.x;
    if (n >= NN_) return;
    int b = batch[n];
    if (n == 0) { for (int g = 0; g <= b; g++) gb[g] = 0; }
    else {
        int pb = batch[n - 1];
        for (int g = pb + 1; g <= b; g++) gb[g] = n;
    }
    if (n == NN_ - 1) { for (int g = b + 1; g <= NG_; g++) gb[g] = NN_; }
}

// ---------------- fused weight transposes (+ fc1W transpose for coalesced k_fc) ----------
__global__ void k_tw(const float* gWih, const float* gWhh, float* WihT, float* WhhT,
                     const float* lWih, const float* lWhh, float* WihT2, float* WhhT2,
                     const float* fc1W, float* fc1WT) {
    int t = blockIdx.x * 256 + threadIdx.x;
    if (t < 12288) {
        int gr = t >> 6, i = t & 63; WihT[i * 192 + gr] = gWih[t];
    } else if (t < 24576) {
        int u = t - 12288; int gr = u >> 6, i = u & 63; WhhT[i * 192 + gr] = gWhh[u];
    } else if (t < 57344) {
        int u = t - 24576; int r = u >> 7, c = u & 127; WihT2[c * 256 + r] = lWih[u];
    } else if (t < 73728) {
        int u = t - 57344; int r = u >> 6, c = u & 63; WhhT2[c * 256 + r] = lWhh[u];
    } else if (t < 90112) {
        int u = t - 73728; int r = u >> 7, c = u & 127; fc1WT[c * 128 + r] = fc1W[u];
    }
}

// ---------------- Bhat3: frag-contiguous bf16 B [s][w][t][lane][8] ----------------
__global__ void k_bhat3(const float* e2W, unsigned short* Bhat3) {
    int idx = blockIdx.x * 256 + threadIdx.x;   // < 524288
    if (idx >= 64 * 4 * 4 * 64 * 8) return;
    int j = idx & 7, lane = (idx >> 3) & 63, t = (idx >> 9) & 3, w = (idx >> 11) & 3, s = idx >> 13;
    int row = s * 64 + w * 16 + (lane & 15);
    int k = t * 32 + (lane >> 4) * 8 + j;
    Bhat3[idx] = f2bfu(e2W[row * 128 + k]);
}

// ---------------- Hhat: frag-ready He in dst-sorted edge order ----------------
__global__ __launch_bounds__(256) void k_he(const float* __restrict__ ea,
                                            const float* __restrict__ e1W,
                                            const float* __restrict__ e1b,
                                            const int* __restrict__ perm,
                                            unsigned short* __restrict__ Hhat) {
    int tid = threadIdx.x;
    int lane = tid & 63, sub = tid >> 6;
    int gi = blockIdx.x * 4 + sub;            // < 12288
    int etile = gi >> 2, t = gi & 3;
    int e = etile * 16 + (lane & 15), quad = lane >> 4;
    int eo = perm[e];
    const float* ar = ea + (size_t)eo * 4;
    float a0 = ar[0], a1 = ar[1], a2 = ar[2], a3 = ar[3];
    union { unsigned short u[8]; uint4 q; } o;
#pragma unroll
    for (int j = 0; j < 8; j++) {
        int c = t * 32 + quad * 8 + j;
        const float* wr = e1W + c * 4;
        float h = e1b[c] + a0 * wr[0] + a1 * wr[1] + a2 * wr[2] + a3 * wr[3];
        o.u[j] = f2bfu(fmaxf(h, 0.f));
    }
    *(uint4*)(Hhat + (size_t)gi * 512 + lane * 8) = o.q;
}

// ---------------- MFMA NNConv (round-10 proven): prefetched body + segment-reduce epilogue ----
#define PS(S) (((S) + soff) & 63)

#define LDB(B, S) {                                                                       \
        const unsigned short* _p = Bhat3 + (size_t)PS(S) * 8192 + w * 2048 + lane * 8;    \
        (B)[0] = *(const bh8*)(const void*)(_p);                                          \
        (B)[1] = *(const bh8*)(const void*)(_p + 512);                                    \
        (B)[2] = *(const bh8*)(const void*)(_p + 1024);                                   \
        (B)[3] = *(const bh8*)(const void*)(_p + 1536); }

#define LDXV(XV, S) {                                                                     \
        int sp_ = PS(S);                                                                  \
        _Pragma("unroll")                                                                 \
        for (int mt_ = 0; mt_ < 4; mt_++)                                                 \
            (XV)[mt_] = *(const f32x4*)(const void*)(xs + sp_ * 68 + mt_ * 16 + quad * 4); }

#define LDBB(BB, S) (BB) = e2b[PS(S) * 64 + w * 16 + mrow];

#define MFMA16(ACC, B) {                                                                  \
        __builtin_amdgcn_s_setprio(1);                                                    \
        _Pragma("unroll")                                                                 \
        for (int t_ = 0; t_ < 4; t_++) {                                                  \
            _Pragma("unroll")                                                             \
            for (int mt_ = 0; mt_ < 4; mt_++)                                             \
                (ACC)[mt_] = __builtin_amdgcn_mfma_f32_16x16x32_bf16(                     \
                    af[mt_][t_], (B)[t_], (t_ == 0) ? z4 : (ACC)[mt_], 0, 0, 0);          \
        }                                                                                 \
        __builtin_amdgcn_s_setprio(0); }

#define CONSUME(ACC, XV, BB) {                                                            \
        _Pragma("unroll")                                                                 \
        for (int mt_ = 0; mt_ < 4; mt_++) {                                               \
            _Pragma("unroll")                                                             \
            for (int r_ = 0; r_ < 4; r_++)                                                \
                msgv[mt_][r_] += (XV)[mt_][r_] * ((ACC)[mt_][r_] + (BB));                 \
        } }

__global__ __launch_bounds__(256, 2) void k_convr(const float* __restrict__ node,
                                                  const unsigned short* __restrict__ Hhat,
                                                  const unsigned short* __restrict__ Bhat3,
                                                  const float* __restrict__ e2b,
                                                  const int* __restrict__ src,
                                                  const int* __restrict__ dst,
                                                  const int* __restrict__ perm,
                                                  float* __restrict__ agg) {
    __shared__ __align__(16) float xs[64 * 68];   // xs[s][e]; reused as msT[e][d] in epilogue
    __shared__ int dst_s[64];

    const int tid = threadIdx.x;
    const int eb = blockIdx.x * 64;
    const int lane = tid & 63, w = tid >> 6;
    const int quad = lane >> 4, mrow = lane & 15;
    const int soff = (blockIdx.x * 37) & 63;

    {
        int r = tid >> 2, c = tid & 3;
        int s = src[perm[eb + r]];
        const float* nr = node + (size_t)s * 64 + c * 16;
#pragma unroll
        for (int j = 0; j < 16; j++) xs[(c * 16 + j) * 68 + r] = nr[j];
        if (tid < 64) dst_s[tid] = dst[perm[eb + tid]];
    }

    bh8 af[4][4];
#pragma unroll
    for (int mt = 0; mt < 4; mt++)
#pragma unroll
        for (int t = 0; t < 4; t++)
            af[mt][t] = *(const bh8*)(const void*)(
                Hhat + (size_t)(((eb >> 4) + mt) * 4 + t) * 512 + lane * 8);
    __syncthreads();

    const f32x4 z4 = {0.f, 0.f, 0.f, 0.f};
    f32x4 msgv[4];
#pragma unroll
    for (int mt = 0; mt < 4; mt++) msgv[mt] = z4;

    bh8 b0[4], b1[4];
    f32x4 xvA[4], xvB[4];
    f32x4 accA[4], accB[4];
    float bbA, bbB;

    // prologue: accA = W(0) issued, b1 = B(1), b0 = B(2), xvA = x(0), bbA = bb(0)
    LDB(b0, 0)
    LDB(b1, 1)
    LDXV(xvA, 0)
    LDBB(bbA, 0)
    MFMA16(accA, b0)
    LDB(b0, 2)

#pragma unroll 1
    for (int s = 0; s < 62; s += 2) {
        MFMA16(accB, b1)          // W(s+1)
        LDB(b1, s + 3)
        LDXV(xvB, s + 1)
        LDBB(bbB, s + 1)
        CONSUME(accA, xvA, bbA)   // consume s
        MFMA16(accA, b0)          // W(s+2)
        LDB(b0, (s + 4) & 63)
        LDXV(xvA, s + 2)
        LDBB(bbA, s + 2)
        CONSUME(accB, xvB, bbB)   // consume s+1
    }
    MFMA16(accB, b1)              // W(63)
    CONSUME(accA, xvA, bbA)       // s = 62
    LDXV(xvB, 63)
    LDBB(bbB, 63)
    CONSUME(accB, xvB, bbB)       // s = 63

    // ---- epilogue: transpose msgv via xs, per-window segment reduce ----
    __syncthreads();   // all waves done reading xs
#pragma unroll
    for (int mt = 0; mt < 4; mt++)
#pragma unroll
        for (int r = 0; r < 4; r++)
            xs[(mt * 16 + quad * 4 + r) * 68 + w * 16 + mrow] = msgv[mt][r];
    __syncthreads();
    {
        const int ebase = w * 16;     // this wave's 16-edge window
        const int d = lane;
        float acc = 0.f;
        int startE = ebase;
        int curn = dst_s[ebase];
#pragma unroll
        for (int e = ebase; e < ebase + 16; e++) {
            acc += xs[e * 68 + d];
            int nxt = (e < ebase + 15) ? dst_s[e + 1] : -1;
            if (nxt != curn) {
                float* dp = agg + (size_t)curn * 64 + d;
                if (startE == ebase || e == ebase + 15) atomicAdd(dp, acc);
                else *dp = acc;
                acc = 0.f; startE = e + 1; curn = nxt;
            }
        }
    }
}

// ---------------- fused m+GRU: 64 nodes/block, 16 nodes/thread (round-13 proven) ----------
// + distance-1 register prefetch on the 6 GRU weight streams and rootW so the per-
// iteration L2 hit latency sits under the previous iteration's 96 FMAs.
__global__ __launch_bounds__(256) void k_mgru(float* __restrict__ agg,
                                              const int* __restrict__ offs,
                                              const float* __restrict__ node,
                                              const float* __restrict__ rootW,
                                              const float* __restrict__ convb,
                                              const float* __restrict__ WihT,
                                              const float* __restrict__ WhhT,
                                              const float* __restrict__ bih,
                                              const float* __restrict__ bhh,
                                              float* __restrict__ hOut) {
    __shared__ __align__(16) float hsT[64][68];   // hsT[i][node], 64 nodes + pad
    __shared__ __align__(16) float msT[64][68];
    const int tid = threadIdx.x;
    const int d = tid & 63, sub = tid >> 6;
    const int nb = blockIdx.x * 64;
    const int r0 = sub * 16;
    const int off = (blockIdx.x * 37) & 63;

    {   // stage h transposed: 16 nodes per thread
#pragma unroll
        for (int j4 = 0; j4 < 4; j4++) {
            f32x4 hv;
#pragma unroll
            for (int j = 0; j < 4; j++)
                hv[j] = node[(size_t)(nb + r0 + j4 * 4 + j) * 64 + d];
            *(f32x4*)&hsT[d][r0 + j4 * 4] = hv;
        }
    }
    __syncthreads();

    {   // m = relu(agg/deg + h@rootW + convb); zero agg; rootW prefetch-1
        float root[16];
#pragma unroll
        for (int j = 0; j < 16; j++) root[j] = 0.f;
        float wv = rootW[off * 64 + d];
        for (int ii = 0; ii < 64; ii++) {
            int i = (ii + off) & 63;
            float wn = rootW[(((ii + 1) + off) & 63) * 64 + d];   // prefetch next
#pragma unroll
            for (int j4 = 0; j4 < 4; j4++) {
                f32x4 h4 = *(const f32x4*)&hsT[i][r0 + j4 * 4];   // broadcast
#pragma unroll
                for (int j = 0; j < 4; j++) root[j4 * 4 + j] += h4[j] * wv;
            }
            wv = wn;
        }
        float cb = convb[d];
#pragma unroll
        for (int j4 = 0; j4 < 4; j4++) {
            f32x4 mval;
#pragma unroll
            for (int j = 0; j < 4; j++) {
                int n = nb + r0 + j4 * 4 + j;
                float dg = (float)(offs[n + 1] - offs[n]);
                float inv = 1.f / fmaxf(dg, 1.f);
                float av = agg[(size_t)n * 64 + d];
                agg[(size_t)n * 64 + d] = 0.f;
                mval[j] = fmaxf(av * inv + cb + root[j4 * 4 + j], 0.f);
            }
            *(f32x4*)&msT[d][r0 + j4 * 4] = mval;
        }
    }
    __syncthreads();

    float ir[16], iz[16], in_[16], hr[16], hz[16], hn[16];
    {
        float bi0 = bih[d], bi1 = bih[64 + d], bi2 = bih[128 + d];
        float bh0 = bhh[d], bh1 = bhh[64 + d], bh2 = bhh[128 + d];
#pragma unroll
        for (int j = 0; j < 16; j++) {
            ir[j] = bi0; iz[j] = bi1; in_[j] = bi2;
            hr[j] = bh0; hz[j] = bh1; hn[j] = bh2;
        }
    }
    // GRU loop with distance-1 register prefetch of the 6 weight streams
    float wi0, wi1, wi2, wh0, wh1, wh2;
    {
        int i0 = off & 63;
        wi0 = WihT[i0 * 192 + d]; wi1 = WihT[i0 * 192 + 64 + d]; wi2 = WihT[i0 * 192 + 128 + d];
        wh0 = WhhT[i0 * 192 + d]; wh1 = WhhT[i0 * 192 + 64 + d]; wh2 = WhhT[i0 * 192 + 128 + d];
    }
#pragma unroll 1
    for (int ii = 0; ii < 64; ii++) {
        int i = (ii + off) & 63;
        int in1 = ((ii + 1) + off) & 63;   // wraps at ii=63: harmless reload of row off
        float ni0 = WihT[in1 * 192 + d];
        float ni1 = WihT[in1 * 192 + 64 + d];
        float ni2 = WihT[in1 * 192 + 128 + d];
        float nh0 = WhhT[in1 * 192 + d];
        float nh1 = WhhT[in1 * 192 + 64 + d];
        float nh2 = WhhT[in1 * 192 + 128 + d];
#pragma unroll
        for (int j4 = 0; j4 < 4; j4++) {
            f32x4 m4 = *(const f32x4*)&msT[i][r0 + j4 * 4];   // broadcast
            f32x4 h4 = *(const f32x4*)&hsT[i][r0 + j4 * 4];   // broadcast
#pragma unroll
            for (int j = 0; j < 4; j++) {
                int jj = j4 * 4 + j;
                ir[jj] += m4[j] * wi0; iz[jj] += m4[j] * wi1; in_[jj] += m4[j] * wi2;
                hr[jj] += h4[j] * wh0; hz[jj] += h4[j] * wh1; hn[jj] += h4[j] * wh2;
            }
        }
        wi0 = ni0; wi1 = ni1; wi2 = ni2;
        wh0 = nh0; wh1 = nh1; wh2 = nh2;
    }
#pragma unroll
    for (int j = 0; j < 16; j++) {
        float hold = hsT[d][r0 + j];
        float r = sigm(ir[j] + hr[j]);
        float z = sigm(iz[j] + hz[j]);
        float nn = tanhf(in_[j] + r * hn[j]);
        hOut[(size_t)(nb + r0 + j) * 64 + d] = (1.f - z) * nn + z * hold;
    }
}

// ---------------- fused Set2Set x3: state in LDS, two-pass parallel softmax readout ----------
__global__ __launch_bounds__(256) void k_s2s3(const float* __restrict__ node,
                                              const int* __restrict__ gb,
                                              const float* __restrict__ WihT2,
                                              const float* __restrict__ WhhT2,
                                              const float* __restrict__ bih,
                                              const float* __restrict__ bhh,
                                              float* __restrict__ qstar) {
    __shared__ float qvs[128];
    __shared__ float hls[64], cls[64], qsh[64];
    __shared__ float accs[4][64];
    __shared__ float es[256];
    __shared__ float red[4][64];
    __shared__ float sred[4];
    const int b = blockIdx.x, tid = threadIdx.x;
    const int lane = tid & 63, wv = tid >> 6;
    const int start = gb[b], end = gb[b + 1];

    if (tid < 128) qvs[tid] = 0.f;
    else if (tid < 192) hls[tid - 128] = 0.f;
    else cls[tid - 192] = 0.f;
    __syncthreads();

    for (int step = 0; step < 3; step++) {
        // LSTM gates: wave wv computes gate wv for all 64 dims
        float acc = bih[wv * 64 + lane] + bhh[wv * 64 + lane];
        if (step > 0) {
            const float* wih = WihT2 + wv * 64 + lane;
            const float* whh = WhhT2 + wv * 64 + lane;
#pragma unroll 4
            for (int j = 0; j < 128; j++) acc += qvs[j] * wih[(size_t)j * 256];
#pragma unroll 4
            for (int j = 0; j < 64; j++) acc += hls[j] * whh[(size_t)j * 256];
        }
        accs[wv][lane] = acc;
        __syncthreads();
        if (tid < 64) {
            float c = sigm(accs[1][tid]) * cls[tid] + sigm(accs[0][tid]) * tanhf(accs[2][tid]);
            cls[tid] = c;
            float q = sigm(accs[3][tid]) * tanhf(c);
            hls[tid] = q; qsh[tid] = q;
        }
        __syncthreads();
        const float q = qsh[lane];

        float m_run = -1e30f, l_run = 0.f, r_part = 0.f;
        for (int cbase = start; cbase < end; cbase += 256) {
            int cn = min(256, end - cbase);
            // pass A: scores (parallel across 4 waves)
            for (int i = wv; i < cn; i += 4) {
                float nv = node[(size_t)(cbase + i) * 64 + lane];
                float p = nv * q;
#pragma unroll
                for (int o = 32; o > 0; o >>= 1) p += __shfl_xor(p, o);
                if (lane == 0) es[i] = p;
            }
            __syncthreads();
            // pass B: chunk max (block reduce)
            float mloc = -1e30f;
            for (int i = tid; i < cn; i += 256) mloc = fmaxf(mloc, es[i]);
#pragma unroll
            for (int o = 32; o > 0; o >>= 1) mloc = fmaxf(mloc, __shfl_xor(mloc, o));
            if (lane == 0) sred[wv] = mloc;
            __syncthreads();
            float m_chunk = fmaxf(fmaxf(sred[0], sred[1]), fmaxf(sred[2], sred[3]));
            float m_new = fmaxf(m_run, m_chunk);
            float sc = expf(m_run - m_new);
            // pass L: weights + chunk sum
            float lloc = 0.f;
            for (int i = tid; i < cn; i += 256) {
                float wgt = expf(es[i] - m_new);
                es[i] = wgt; lloc += wgt;
            }
#pragma unroll
            for (int o = 32; o > 0; o >>= 1) lloc += __shfl_xor(lloc, o);
            __syncthreads();
            if (lane == 0) sred[wv] = lloc;
            __syncthreads();
            float l_chunk = sred[0] + sred[1] + sred[2] + sred[3];
            l_run = l_run * sc + l_chunk;
            // pass C: weighted node-row sum
            r_part *= sc;
            for (int i = wv; i < cn; i += 4)
                r_part += es[i] * node[(size_t)(cbase + i) * 64 + lane];
            m_run = m_new;
            __syncthreads();   // es reused next chunk
        }
        red[wv][lane] = r_part;
        __syncthreads();
        if (tid < 64) {
            float r = red[0][tid] + red[1][tid] + red[2][tid] + red[3][tid];
            qvs[tid] = qsh[tid];
            qvs[64 + tid] = (end > start) ? r / l_run : 0.f;
        }
        __syncthreads();
    }
    if (tid < 128) qstar[(size_t)b * 128 + tid] = qvs[tid];
}

// ---------------- head (coalesced via transposed fc1W) ----------------
__global__ void k_fc(const float* qstar, const float* W1T, const float* b1,
                     const float* W2, const float* b2, float* out) {
    __shared__ float hid[128];
    __shared__ float qs[128];
    int b = blockIdx.x; int t = threadIdx.x;  // 128 threads
    qs[t] = qstar[(size_t)b * 128 + t];
    __syncthreads();
    float acc = b1[t];
    for (int k = 0; k < 128; k++) acc += qs[k] * W1T[k * 128 + t];
    hid[t] = fmaxf(acc, 0.f);
    __syncthreads();
    if (t < 64) {
        float s = hid[t] * W2[t] + hid[t + 64] * W2[t + 64];
        for (int o = 32; o > 0; o >>= 1) s += __shfl_xor(s, o);
        if (t == 0) out[b] = s + b2[0];
    }
}

extern "C" void kernel_launch(void* const* d_in, const int* in_sizes, int n_in,
                              void* d_out, int out_size, void* d_ws, size_t ws_size,
                              hipStream_t stream) {
    const float* x     = (const float*)d_in[0];
    const int*   ei    = (const int*)d_in[1];
    const float* ea    = (const float*)d_in[2];
    const int*   batch = (const int*)d_in[3];
    const float* lin0W = (const float*)d_in[4];
    const float* lin0b = (const float*)d_in[5];
    const float* e1W   = (const float*)d_in[6];
    const float* e1b   = (const float*)d_in[7];
    const float* e2W   = (const float*)d_in[8];
    const float* e2b   = (const float*)d_in[9];
    const float* rootW = (const float*)d_in[10];
    const float* convb = (const float*)d_in[11];
    const float* gWih  = (const float*)d_in[12];
    const float* gWhh  = (const float*)d_in[13];
    const float* gbih  = (const float*)d_in[14];
    const float* gbhh  = (const float*)d_in[15];
    const float* lWih  = (const float*)d_in[16];
    const float* lWhh  = (const float*)d_in[17];
    const float* lbih  = (const float*)d_in[18];
    const float* lbhh  = (const float*)d_in[19];
    const float* fc1W  = (const float*)d_in[20];
    const float* fc1b  = (const float*)d_in[21];
    const float* fc2W  = (const float*)d_in[22];
    const float* fc2b  = (const float*)d_in[23];
    const int* src = ei;
    const int* dst = ei + NE_;

    // workspace carve (~33 MB)
    char* p = (char*)d_ws;
    auto alloc = [&](size_t bytes) -> char* {
        char* r = p; p += (bytes + 255) & ~(size_t)255; return r;
    };
    unsigned short* Bhat3 = (unsigned short*)alloc((size_t)524288 * 2);        // 1.05 MB
    unsigned short* Hhat  = (unsigned short*)alloc((size_t)NE_ * 128 * 2);     // 12.6 MB
    float* nodeA  = (float*)alloc((size_t)NN_ * 64 * 4);
    float* nodeB  = (float*)alloc((size_t)NN_ * 64 * 4);
    float* aggb   = (float*)alloc((size_t)NN_ * 64 * 4);
    int*   deg    = (int*)alloc((size_t)NN_ * 4);
    int*   offs   = (int*)alloc((size_t)(NN_ + 1) * 4);
    int*   head   = (int*)alloc((size_t)NN_ * 4);
    int*   perm   = (int*)alloc((size_t)NE_ * 4);
    int*   bsum   = (int*)alloc((size_t)128 * 4);
    int*   gb     = (int*)alloc((size_t)(NG_ + 1) * 4);
    float* WihT   = (float*)alloc(192 * 64 * 4);
    float* WhhT   = (float*)alloc(192 * 64 * 4);
    float* WihT2  = (float*)alloc(256 * 128 * 4);
    float* WhhT2  = (float*)alloc(256 * 64 * 4);
    float* fc1WT  = (float*)alloc(128 * 128 * 4);
    float* qstar  = (float*)alloc((size_t)NG_ * 128 * 4);

    k_init<<<(NN_ + NN_ * 64 + 255) / 256, 256, 0, stream>>>(deg, aggb);
    k_lin0<<<NN_ * 64 / 256, 256, 0, stream>>>(x, lin0W, lin0b, nodeA);
    k_cnt<<<NE_ / 256, 256, 0, stream>>>(dst, deg);
    k_scanA<<<NN_ / 256, 256, 0, stream>>>(deg, offs, bsum);
    k_scanC<<<NN_ / 256, 256, 0, stream>>>(bsum, offs, head);
    k_scatter<<<NE_ / 256, 256, 0, stream>>>(dst, head, perm);
    k_gbnd<<<NN_ / 256, 256, 0, stream>>>(batch, gb);
    k_tw<<<352, 256, 0, stream>>>(gWih, gWhh, WihT, WhhT, lWih, lWhh, WihT2, WhhT2,
                                  fc1W, fc1WT);
    k_bhat3<<<524288 / 256, 256, 0, stream>>>(e2W, Bhat3);
    k_he<<<NE_ / 16, 256, 0, stream>>>(ea, e1W, e1b, perm, Hhat);   // sorted edge order

    float* curF = nodeA; float* nxtF = nodeB;
    for (int it = 0; it < 3; it++) {
        k_convr<<<NE_ / 64, 256, 0, stream>>>(curF, Hhat, Bhat3, e2b, src, dst, perm, aggb);
        k_mgru<<<NN_ / 64, 256, 0, stream>>>(aggb, offs, curF, rootW, convb,
                                             WihT, WhhT, gbih, gbhh, nxtF);
        float* tf = curF; curF = nxtF; nxtF = tf;
    }

    k_s2s3<<<NG_, 256, 0, stream>>>(curF, gb, WihT2, WhhT2, lbih, lbhh, qstar);
    k_fc<<<NG_, 128, 0, stream>>>(qstar, fc1WT, fc1b, fc2W, fc2b, (float*)d_out);
}

// Round 16
// 425.175 us; speedup vs baseline: 1.0954x; 1.0692x over previous
//
#include <hip/hip_runtime.h>
#include <math.h>

#define NN_ 32768      // nodes
#define NE_ 49152      // edges
#define NG_ 1024       // graphs

typedef short bh8 __attribute__((ext_vector_type(8)));   // 8 bf16 bit-patterns (4 VGPR)
typedef float f32x4 __attribute__((ext_vector_type(4)));

__device__ __forceinline__ unsigned short f2bfu(float f) {   // RNE float->bf16 bits
    union { float f; unsigned int i; } x; x.f = f;
    unsigned int u = x.i;
    u += 0x7FFFu + ((u >> 16) & 1u);
    return (unsigned short)(u >> 16);
}
__device__ __forceinline__ float sigm(float x) { return 1.f / (1.f + expf(-x)); }

// Kept for harness compatibility (unused).
__global__ void MPNN_78632261256134_kernel() {}

// ---------------- fused init zero: deg (int) | agg ----------------
__global__ void k_init(int* deg, float* agg) {
    int i = blockIdx.x * 256 + threadIdx.x;
    if (i < NN_) deg[i] = 0;
    int k = i - NN_;
    if (k >= 0 && k < NN_ * 64) agg[k] = 0.f;
}

// ---------------- lin0 ----------------
__global__ void k_lin0(const float* x, const float* W, const float* b, float* node) {
    int g = blockIdx.x * 256 + threadIdx.x;   // n*64+d
    int n = g >> 6, d = g & 63;
    const float* xr = x + n * 14;
    const float* wr = W + d * 14;
    float acc = b[d];
    for (int i = 0; i < 14; i++) acc += xr[i] * wr[i];
    node[g] = fmaxf(acc, 0.f);
}

// ---------------- in-degree count (int) ----------------
__global__ void k_cnt(const int* dst, int* deg) {
    int e = blockIdx.x * 256 + threadIdx.x;
    if (e < NE_) atomicAdd(&deg[dst[e]], 1);
}

// ---------------- two-phase parallel prefix scan ----------------
__global__ __launch_bounds__(256) void k_scanA(const int* __restrict__ deg,
                                               int* __restrict__ offs,
                                               int* __restrict__ bsum) {
    __shared__ int wtot[4];
    int tid = threadIdx.x, bid = blockIdx.x;
    int i = bid * 256 + tid;
    int v = deg[i];
    int sc = v;
    for (int o = 1; o < 64; o <<= 1) { int u = __shfl_up(sc, o); if ((tid & 63) >= o) sc += u; }
    if ((tid & 63) == 63) wtot[tid >> 6] = sc;
    __syncthreads();
    int wpre = 0;
    for (int k = 0; k < (tid >> 6); k++) wpre += wtot[k];
    offs[i] = sc + wpre - v;              // exclusive within block
    if (tid == 255) bsum[bid] = sc + wpre; // block total
}

__global__ __launch_bounds__(256) void k_scanC(const int* __restrict__ bsum,
                                               int* __restrict__ offs,
                                               int* __restrict__ head) {
    __shared__ int boff;
    int tid = threadIdx.x, bid = blockIdx.x;
    if (tid == 0) {
        int s = 0;
        for (int k = 0; k < bid; k++) s += bsum[k];
        boff = s;
    }
    __syncthreads();
    int i = bid * 256 + tid;
    int o = offs[i] + boff;
    offs[i] = o; head[i] = o;
    if (i == NN_ - 1) offs[NN_] = NE_;
}

// ---------------- scatter: perm = edges sorted by dst (counting sort) ----------------
__global__ void k_scatter(const int* __restrict__ dst, int* __restrict__ head,
                          int* __restrict__ perm) {
    int e = blockIdx.x * 256 + threadIdx.x;
    if (e < NE_) { int p = atomicAdd(&head[dst[e]], 1); perm[p] = e; }
}

// ---------------- graph segment bounds for Set2Set ----------------
__global__ void k_gbnd(const int* __restrict__ batch, int* __restrict__ gb) {
    int n = blockIdx.x * 256 + threadIdx.x;
    if (n >= NN_) return;
    int b = batch[n];
    if (n == 0) { for (int g = 0; g <= b; g++) gb[g] = 0; }
    else {
        int pb = batch[n - 1];
        for (int g = pb + 1; g <= b; g++) gb[g] = n;
    }
    if (n == NN_ - 1) { for (int g = b + 1; g <= NG_; g++) gb[g] = NN_; }
}

// ---------------- weight transposes for s2s3/fc ----------------
__global__ void k_tw(const float* lWih, const float* lWhh, float* WihT2, float* WhhT2,
                     const float* fc1W, float* fc1WT) {
    int t = blockIdx.x * 256 + threadIdx.x;
    if (t < 32768) {
        int r = t >> 7, cc = t & 127; WihT2[cc * 256 + r] = lWih[t];
    } else if (t < 49152) {
        int u = t - 32768; int r = u >> 6, cc = u & 63; WhhT2[cc * 256 + r] = lWhh[u];
    } else if (t < 65536) {
        int u = t - 49152; int r = u >> 7, cc = u & 127; fc1WT[cc * 128 + r] = fc1W[u];
    }
}

// ---------------- GRU weight B-fragments, bf16x2 hi/lo (once) ----------------
// HH part: [WhhT | rootW] as K=64 x N=256 -> 16 ot x 2 kt tiles of 512 shorts.
// IH part: WihT as K=64 x N=192 -> 12 ot x 2 kt tiles.
// frag element: col = ot*16 + (lane&15), k = kt*32 + (lane>>4)*8 + j  (same
// convention as k_bhat3 / verified convr B-frags).
__global__ void k_wfrag(const float* __restrict__ gWih, const float* __restrict__ gWhh,
                        const float* __restrict__ rootW,
                        unsigned short* __restrict__ HHh, unsigned short* __restrict__ HHl,
                        unsigned short* __restrict__ IHh, unsigned short* __restrict__ IHl) {
    int idx = blockIdx.x * 256 + threadIdx.x;   // < 28672
    if (idx >= 28672) return;
    float w;
    unsigned short *oh, *ol;
    if (idx < 16384) {
        int f = idx;
        int tile = f >> 9, within = f & 511;
        int l = within >> 3, j = within & 7;
        int ot = tile >> 1, kt = tile & 1;
        int col = ot * 16 + (l & 15);
        int k = kt * 32 + (l >> 4) * 8 + j;
        w = (col < 192) ? gWhh[col * 64 + k] : rootW[k * 64 + (col - 192)];
        oh = HHh + f; ol = HHl + f;
    } else {
        int f = idx - 16384;
        int tile = f >> 9, within = f & 511;
        int l = within >> 3, j = within & 7;
        int ot = tile >> 1, kt = tile & 1;
        int col = ot * 16 + (l & 15);
        int k = kt * 32 + (l >> 4) * 8 + j;
        w = gWih[col * 64 + k];
        oh = IHh + f; ol = IHl + f;
    }
    unsigned short hi = f2bfu(w);
    union { unsigned int i; float f; } hv; hv.i = (unsigned int)hi << 16;
    unsigned short lo = f2bfu(w - hv.f);
    *oh = hi; *ol = lo;
}

// ---------------- Bhat3: frag-contiguous bf16 B [s][w][t][lane][8] ----------------
__global__ void k_bhat3(const float* e2W, unsigned short* Bhat3) {
    int idx = blockIdx.x * 256 + threadIdx.x;   // < 524288
    if (idx >= 64 * 4 * 4 * 64 * 8) return;
    int j = idx & 7, lane = (idx >> 3) & 63, t = (idx >> 9) & 3, w = (idx >> 11) & 3, s = idx >> 13;
    int row = s * 64 + w * 16 + (lane & 15);
    int k = t * 32 + (lane >> 4) * 8 + j;
    Bhat3[idx] = f2bfu(e2W[row * 128 + k]);
}

// ---------------- Hhat: frag-ready He in dst-sorted edge order ----------------
__global__ __launch_bounds__(256) void k_he(const float* __restrict__ ea,
                                            const float* __restrict__ e1W,
                                            const float* __restrict__ e1b,
                                            const int* __restrict__ perm,
                                            unsigned short* __restrict__ Hhat) {
    int tid = threadIdx.x;
    int lane = tid & 63, sub = tid >> 6;
    int gi = blockIdx.x * 4 + sub;            // < 12288
    int etile = gi >> 2, t = gi & 3;
    int e = etile * 16 + (lane & 15), quad = lane >> 4;
    int eo = perm[e];
    const float* ar = ea + (size_t)eo * 4;
    float a0 = ar[0], a1 = ar[1], a2 = ar[2], a3 = ar[3];
    union { unsigned short u[8]; uint4 q; } o;
#pragma unroll
    for (int j = 0; j < 8; j++) {
        int c = t * 32 + quad * 8 + j;
        const float* wr = e1W + c * 4;
        float h = e1b[c] + a0 * wr[0] + a1 * wr[1] + a2 * wr[2] + a3 * wr[3];
        o.u[j] = f2bfu(fmaxf(h, 0.f));
    }
    *(uint4*)(Hhat + (size_t)gi * 512 + lane * 8) = o.q;
}

// ---------------- MFMA NNConv (round-10 proven): prefetched body + segment-reduce epilogue ----
#define PS(S) (((S) + soff) & 63)

#define LDB(B, S) {                                                                       \
        const unsigned short* _p = Bhat3 + (size_t)PS(S) * 8192 + w * 2048 + lane * 8;    \
        (B)[0] = *(const bh8*)(const void*)(_p);                                          \
        (B)[1] = *(const bh8*)(const void*)(_p + 512);                                    \
        (B)[2] = *(const bh8*)(const void*)(_p + 1024);                                   \
        (B)[3] = *(const bh8*)(const void*)(_p + 1536); }

#define LDXV(XV, S) {                                                                     \
        int sp_ = PS(S);                                                                  \
        _Pragma("unroll")                                                                 \
        for (int mt_ = 0; mt_ < 4; mt_++)                                                 \
            (XV)[mt_] = *(const f32x4*)(const void*)(xs + sp_ * 68 + mt_ * 16 + quad * 4); }

#define LDBB(BB, S) (BB) = e2b[PS(S) * 64 + w * 16 + mrow];

#define MFMA16(ACC, B) {                                                                  \
        __builtin_amdgcn_s_setprio(1);                                                    \
        _Pragma("unroll")                                                                 \
        for (int t_ = 0; t_ < 4; t_++) {                                                  \
            _Pragma("unroll")                                                             \
            for (int mt_ = 0; mt_ < 4; mt_++)                                             \
                (ACC)[mt_] = __builtin_amdgcn_mfma_f32_16x16x32_bf16(                     \
                    af[mt_][t_], (B)[t_], (t_ == 0) ? z4 : (ACC)[mt_], 0, 0, 0);          \
        }                                                                                 \
        __builtin_amdgcn_s_setprio(0); }

#define CONSUME(ACC, XV, BB) {                                                            \
        _Pragma("unroll")                                                                 \
        for (int mt_ = 0; mt_ < 4; mt_++) {                                               \
            _Pragma("unroll")                                                             \
            for (int r_ = 0; r_ < 4; r_++)                                                \
                msgv[mt_][r_] += (XV)[mt_][r_] * ((ACC)[mt_][r_] + (BB));                 \
        } }

__global__ __launch_bounds__(256, 2) void k_convr(const float* __restrict__ node,
                                                  const unsigned short* __restrict__ Hhat,
                                                  const unsigned short* __restrict__ Bhat3,
                                                  const float* __restrict__ e2b,
                                                  const int* __restrict__ src,
                                                  const int* __restrict__ dst,
                                                  const int* __restrict__ perm,
                                                  float* __restrict__ agg) {
    __shared__ __align__(16) float xs[64 * 68];   // xs[s][e]; reused as msT[e][d] in epilogue
    __shared__ int dst_s[64];

    const int tid = threadIdx.x;
    const int eb = blockIdx.x * 64;
    const int lane = tid & 63, w = tid >> 6;
    const int quad = lane >> 4, mrow = lane & 15;
    const int soff = (blockIdx.x * 37) & 63;

    {
        int r = tid >> 2, c = tid & 3;
        int s = src[perm[eb + r]];
        const float* nr = node + (size_t)s * 64 + c * 16;
#pragma unroll
        for (int j = 0; j < 16; j++) xs[(c * 16 + j) * 68 + r] = nr[j];
        if (tid < 64) dst_s[tid] = dst[perm[eb + tid]];
    }

    bh8 af[4][4];
#pragma unroll
    for (int mt = 0; mt < 4; mt++)
#pragma unroll
        for (int t = 0; t < 4; t++)
            af[mt][t] = *(const bh8*)(const void*)(
                Hhat + (size_t)(((eb >> 4) + mt) * 4 + t) * 512 + lane * 8);
    __syncthreads();

    const f32x4 z4 = {0.f, 0.f, 0.f, 0.f};
    f32x4 msgv[4];
#pragma unroll
    for (int mt = 0; mt < 4; mt++) msgv[mt] = z4;

    bh8 b0[4], b1[4];
    f32x4 xvA[4], xvB[4];
    f32x4 accA[4], accB[4];
    float bbA, bbB;

    // prologue: accA = W(0) issued, b1 = B(1), b0 = B(2), xvA = x(0), bbA = bb(0)
    LDB(b0, 0)
    LDB(b1, 1)
    LDXV(xvA, 0)
    LDBB(bbA, 0)
    MFMA16(accA, b0)
    LDB(b0, 2)

#pragma unroll 1
    for (int s = 0; s < 62; s += 2) {
        MFMA16(accB, b1)          // W(s+1)
        LDB(b1, s + 3)
        LDXV(xvB, s + 1)
        LDBB(bbB, s + 1)
        CONSUME(accA, xvA, bbA)   // consume s
        MFMA16(accA, b0)          // W(s+2)
        LDB(b0, (s + 4) & 63)
        LDXV(xvA, s + 2)
        LDBB(bbA, s + 2)
        CONSUME(accB, xvB, bbB)   // consume s+1
    }
    MFMA16(accB, b1)              // W(63)
    CONSUME(accA, xvA, bbA)       // s = 62
    LDXV(xvB, 63)
    LDBB(bbB, 63)
    CONSUME(accB, xvB, bbB)       // s = 63

    // ---- epilogue: transpose msgv via xs, per-window segment reduce ----
    __syncthreads();   // all waves done reading xs
#pragma unroll
    for (int mt = 0; mt < 4; mt++)
#pragma unroll
        for (int r = 0; r < 4; r++)
            xs[(mt * 16 + quad * 4 + r) * 68 + w * 16 + mrow] = msgv[mt][r];
    __syncthreads();
    {
        const int ebase = w * 16;     // this wave's 16-edge window
        const int d = lane;
        float acc = 0.f;
        int startE = ebase;
        int curn = dst_s[ebase];
#pragma unroll
        for (int e = ebase; e < ebase + 16; e++) {
            acc += xs[e * 68 + d];
            int nxt = (e < ebase + 15) ? dst_s[e + 1] : -1;
            if (nxt != curn) {
                float* dp = agg + (size_t)curn * 64 + d;
                if (startE == ebase || e == ebase + 15) atomicAdd(dp, acc);
                else *dp = acc;
                acc = 0.f; startE = e + 1; curn = nxt;
            }
        }
    }
}

// ---------------- MFMA m+GRU: h-GEMM (WhhT|rootW) + m + m-GEMM (WihT) + gates ----------
// 64 nodes/block, 4 waves; wave wvt owns node row-tile wvt. bf16x2 (hi+lo, 3 MFMAs per
// product) keeps fp32-level accuracy. D-layout (col=lane&15, row=(lane>>4)*4+reg) hands
// each thread 4 nodes x 4 dims of every gate, so the elementwise GRU is register-local.
__global__ __launch_bounds__(256) void k_mgru(float* __restrict__ agg,
                                              const int* __restrict__ offs,
                                              const float* __restrict__ node,
                                              const unsigned short* __restrict__ HHh,
                                              const unsigned short* __restrict__ HHl,
                                              const unsigned short* __restrict__ IHh,
                                              const unsigned short* __restrict__ IHl,
                                              const float* __restrict__ convb,
                                              const float* __restrict__ bih,
                                              const float* __restrict__ bhh,
                                              float* __restrict__ hOut) {
    __shared__ __align__(16) float hs[64][68];   // h, node-major
    __shared__ __align__(16) float ms[64][68];   // m, node-major
    const int tid = threadIdx.x;
    const int lane = tid & 63, wvt = tid >> 6;
    const int quad = lane >> 4, c = lane & 15;
    const int nb = blockIdx.x * 64;
    const f32x4 z4 = {0.f, 0.f, 0.f, 0.f};

    {   // stage h [node][dim]
        int n = tid >> 2, dc = (tid & 3) * 16;
        const float* nr = node + (size_t)(nb + n) * 64 + dc;
#pragma unroll
        for (int j4 = 0; j4 < 4; j4++)
            *(f32x4*)&hs[n][dc + j4 * 4] = *(const f32x4*)(nr + j4 * 4);
    }
    __syncthreads();

    // A-frags of h (hi/lo), row-tile wvt
    bh8 ah[2], al[2];
#pragma unroll
    for (int kt = 0; kt < 2; kt++) {
#pragma unroll
        for (int j = 0; j < 8; j++) {
            float x = hs[wvt * 16 + c][kt * 32 + quad * 8 + j];
            unsigned short h = f2bfu(x);
            union { unsigned int i; float f; } hv; hv.i = (unsigned int)h << 16;
            unsigned short l = f2bfu(x - hv.f);
            ah[kt][j] = (short)h; al[kt][j] = (short)l;
        }
    }

    // h-GEMM: D[64x256] = h @ [WhhT | rootW]
    f32x4 hacc[16];
#pragma unroll
    for (int ot = 0; ot < 16; ot++) {
        f32x4 a = z4;
#pragma unroll
        for (int kt = 0; kt < 2; kt++) {
            bh8 bh = *(const bh8*)(const void*)(HHh + (ot * 2 + kt) * 512 + lane * 8);
            bh8 bl = *(const bh8*)(const void*)(HHl + (ot * 2 + kt) * 512 + lane * 8);
            a = __builtin_amdgcn_mfma_f32_16x16x32_bf16(ah[kt], bh, a, 0, 0, 0);
            a = __builtin_amdgcn_mfma_f32_16x16x32_bf16(ah[kt], bl, a, 0, 0, 0);
            a = __builtin_amdgcn_mfma_f32_16x16x32_bf16(al[kt], bh, a, 0, 0, 0);
        }
        hacc[ot] = a;
    }

    // m = relu(agg/deg + convb + root); zero agg; stage m
    int nrow[4]; float invd[4];
#pragma unroll
    for (int r = 0; r < 4; r++) {
        nrow[r] = nb + wvt * 16 + quad * 4 + r;
        int dg = offs[nrow[r] + 1] - offs[nrow[r]];
        invd[r] = 1.f / fmaxf((float)dg, 1.f);
    }
#pragma unroll
    for (int k = 0; k < 4; k++) {
        float cb = convb[c + 16 * k];
#pragma unroll
        for (int r = 0; r < 4; r++) {
            size_t ai = (size_t)nrow[r] * 64 + c + 16 * k;
            float m = fmaxf(agg[ai] * invd[r] + cb + hacc[12 + k][r], 0.f);
            agg[ai] = 0.f;
            ms[wvt * 16 + quad * 4 + r][c + 16 * k] = m;
        }
    }
    __syncthreads();

    // A-frags of m (hi/lo)
    bh8 amh[2], aml[2];
#pragma unroll
    for (int kt = 0; kt < 2; kt++) {
#pragma unroll
        for (int j = 0; j < 8; j++) {
            float x = ms[wvt * 16 + c][kt * 32 + quad * 8 + j];
            unsigned short h = f2bfu(x);
            union { unsigned int i; float f; } hv; hv.i = (unsigned int)h << 16;
            unsigned short l = f2bfu(x - hv.f);
            amh[kt][j] = (short)h; aml[kt][j] = (short)l;
        }
    }

    // m-GEMM: D[64x192] = m @ WihT
    f32x4 macc[12];
#pragma unroll
    for (int ot = 0; ot < 12; ot++) {
        f32x4 a = z4;
#pragma unroll
        for (int kt = 0; kt < 2; kt++) {
            bh8 bh = *(const bh8*)(const void*)(IHh + (ot * 2 + kt) * 512 + lane * 8);
            bh8 bl = *(const bh8*)(const void*)(IHl + (ot * 2 + kt) * 512 + lane * 8);
            a = __builtin_amdgcn_mfma_f32_16x16x32_bf16(amh[kt], bh, a, 0, 0, 0);
            a = __builtin_amdgcn_mfma_f32_16x16x32_bf16(amh[kt], bl, a, 0, 0, 0);
            a = __builtin_amdgcn_mfma_f32_16x16x32_bf16(aml[kt], bh, a, 0, 0, 0);
        }
        macc[ot] = a;
    }

    // elementwise GRU
#pragma unroll
    for (int k = 0; k < 4; k++) {
        int d = c + 16 * k;
        float bir = bih[d], biz = bih[64 + d], bin = bih[128 + d];
        float bhr = bhh[d], bhz = bhh[64 + d], bhn = bhh[128 + d];
#pragma unroll
        for (int r = 0; r < 4; r++) {
            float rr = sigm(macc[k][r] + bir + hacc[k][r] + bhr);
            float zz = sigm(macc[4 + k][r] + biz + hacc[4 + k][r] + bhz);
            float hnv = hacc[8 + k][r] + bhn;
            float nn = tanhf(macc[8 + k][r] + bin + rr * hnv);
            float hold = hs[wvt * 16 + quad * 4 + r][d];
            hOut[(size_t)nrow[r] * 64 + d] = (1.f - zz) * nn + zz * hold;
        }
    }
}

// ---------------- fused Set2Set x3: state in LDS, two-pass parallel softmax readout ----------
__global__ __launch_bounds__(256) void k_s2s3(const float* __restrict__ node,
                                              const int* __restrict__ gb,
                                              const float* __restrict__ WihT2,
                                              const float* __restrict__ WhhT2,
                                              const float* __restrict__ bih,
                                              const float* __restrict__ bhh,
                                              float* __restrict__ qstar) {
    __shared__ float qvs[128];
    __shared__ float hls[64], cls[64], qsh[64];
    __shared__ float accs[4][64];
    __shared__ float es[256];
    __shared__ float red[4][64];
    __shared__ float sred[4];
    const int b = blockIdx.x, tid = threadIdx.x;
    const int lane = tid & 63, wv = tid >> 6;
    const int start = gb[b], end = gb[b + 1];

    if (tid < 128) qvs[tid] = 0.f;
    else if (tid < 192) hls[tid - 128] = 0.f;
    else cls[tid - 192] = 0.f;
    __syncthreads();

    for (int step = 0; step < 3; step++) {
        float acc = bih[wv * 64 + lane] + bhh[wv * 64 + lane];
        if (step > 0) {
            const float* wih = WihT2 + wv * 64 + lane;
            const float* whh = WhhT2 + wv * 64 + lane;
#pragma unroll 4
            for (int j = 0; j < 128; j++) acc += qvs[j] * wih[(size_t)j * 256];
#pragma unroll 4
            for (int j = 0; j < 64; j++) acc += hls[j] * whh[(size_t)j * 256];
        }
        accs[wv][lane] = acc;
        __syncthreads();
        if (tid < 64) {
            float c = sigm(accs[1][tid]) * cls[tid] + sigm(accs[0][tid]) * tanhf(accs[2][tid]);
            cls[tid] = c;
            float q = sigm(accs[3][tid]) * tanhf(c);
            hls[tid] = q; qsh[tid] = q;
        }
        __syncthreads();
        const float q = qsh[lane];

        float m_run = -1e30f, l_run = 0.f, r_part = 0.f;
        for (int cbase = start; cbase < end; cbase += 256) {
            int cn = min(256, end - cbase);
            for (int i = wv; i < cn; i += 4) {
                float nv = node[(size_t)(cbase + i) * 64 + lane];
                float p = nv * q;
#pragma unroll
                for (int o = 32; o > 0; o >>= 1) p += __shfl_xor(p, o);
                if (lane == 0) es[i] = p;
            }
            __syncthreads();
            float mloc = -1e30f;
            for (int i = tid; i < cn; i += 256) mloc = fmaxf(mloc, es[i]);
#pragma unroll
            for (int o = 32; o > 0; o >>= 1) mloc = fmaxf(mloc, __shfl_xor(mloc, o));
            if (lane == 0) sred[wv] = mloc;
            __syncthreads();
            float m_chunk = fmaxf(fmaxf(sred[0], sred[1]), fmaxf(sred[2], sred[3]));
            float m_new = fmaxf(m_run, m_chunk);
            float sc = expf(m_run - m_new);
            float lloc = 0.f;
            for (int i = tid; i < cn; i += 256) {
                float wgt = expf(es[i] - m_new);
                es[i] = wgt; lloc += wgt;
            }
#pragma unroll
            for (int o = 32; o > 0; o >>= 1) lloc += __shfl_xor(lloc, o);
            __syncthreads();
            if (lane == 0) sred[wv] = lloc;
            __syncthreads();
            float l_chunk = sred[0] + sred[1] + sred[2] + sred[3];
            l_run = l_run * sc + l_chunk;
            r_part *= sc;
            for (int i = wv; i < cn; i += 4)
                r_part += es[i] * node[(size_t)(cbase + i) * 64 + lane];
            m_run = m_new;
            __syncthreads();
        }
        red[wv][lane] = r_part;
        __syncthreads();
        if (tid < 64) {
            float r = red[0][tid] + red[1][tid] + red[2][tid] + red[3][tid];
            qvs[tid] = qsh[tid];
            qvs[64 + tid] = (end > start) ? r / l_run : 0.f;
        }
        __syncthreads();
    }
    if (tid < 128) qstar[(size_t)b * 128 + tid] = qvs[tid];
}

// ---------------- head (coalesced via transposed fc1W) ----------------
__global__ void k_fc(const float* qstar, const float* W1T, const float* b1,
                     const float* W2, const float* b2, float* out) {
    __shared__ float hid[128];
    __shared__ float qs[128];
    int b = blockIdx.x; int t = threadIdx.x;  // 128 threads
    qs[t] = qstar[(size_t)b * 128 + t];
    __syncthreads();
    float acc = b1[t];
    for (int k = 0; k < 128; k++) acc += qs[k] * W1T[k * 128 + t];
    hid[t] = fmaxf(acc, 0.f);
    __syncthreads();
    if (t < 64) {
        float s = hid[t] * W2[t] + hid[t + 64] * W2[t + 64];
        for (int o = 32; o > 0; o >>= 1) s += __shfl_xor(s, o);
        if (t == 0) out[b] = s + b2[0];
    }
}

extern "C" void kernel_launch(void* const* d_in, const int* in_sizes, int n_in,
                              void* d_out, int out_size, void* d_ws, size_t ws_size,
                              hipStream_t stream) {
    const float* x     = (const float*)d_in[0];
    const int*   ei    = (const int*)d_in[1];
    const float* ea    = (const float*)d_in[2];
    const int*   batch = (const int*)d_in[3];
    const float* lin0W = (const float*)d_in[4];
    const float* lin0b = (const float*)d_in[5];
    const float* e1W   = (const float*)d_in[6];
    const float* e1b   = (const float*)d_in[7];
    const float* e2W   = (const float*)d_in[8];
    const float* e2b   = (const float*)d_in[9];
    const float* rootW = (const float*)d_in[10];
    const float* convb = (const float*)d_in[11];
    const float* gWih  = (const float*)d_in[12];
    const float* gWhh  = (const float*)d_in[13];
    const float* gbih  = (const float*)d_in[14];
    const float* gbhh  = (const float*)d_in[15];
    const float* lWih  = (const float*)d_in[16];
    const float* lWhh  = (const float*)d_in[17];
    const float* lbih  = (const float*)d_in[18];
    const float* lbhh  = (const float*)d_in[19];
    const float* fc1W  = (const float*)d_in[20];
    const float* fc1b  = (const float*)d_in[21];
    const float* fc2W  = (const float*)d_in[22];
    const float* fc2b  = (const float*)d_in[23];
    const int* src = ei;
    const int* dst = ei + NE_;

    // workspace carve (~33 MB)
    char* p = (char*)d_ws;
    auto alloc = [&](size_t bytes) -> char* {
        char* r = p; p += (bytes + 255) & ~(size_t)255; return r;
    };
    unsigned short* Bhat3 = (unsigned short*)alloc((size_t)524288 * 2);        // 1.05 MB
    unsigned short* Hhat  = (unsigned short*)alloc((size_t)NE_ * 128 * 2);     // 12.6 MB
    float* nodeA  = (float*)alloc((size_t)NN_ * 64 * 4);
    float* nodeB  = (float*)alloc((size_t)NN_ * 64 * 4);
    float* aggb   = (float*)alloc((size_t)NN_ * 64 * 4);
    int*   deg    = (int*)alloc((size_t)NN_ * 4);
    int*   offs   = (int*)alloc((size_t)(NN_ + 1) * 4);
    int*   head   = (int*)alloc((size_t)NN_ * 4);
    int*   perm   = (int*)alloc((size_t)NE_ * 4);
    int*   bsum   = (int*)alloc((size_t)128 * 4);
    int*   gb     = (int*)alloc((size_t)(NG_ + 1) * 4);
    unsigned short* HHh = (unsigned short*)alloc((size_t)16384 * 2);
    unsigned short* HHl = (unsigned short*)alloc((size_t)16384 * 2);
    unsigned short* IHh = (unsigned short*)alloc((size_t)12288 * 2);
    unsigned short* IHl = (unsigned short*)alloc((size_t)12288 * 2);
    float* WihT2  = (float*)alloc(256 * 128 * 4);
    float* WhhT2  = (float*)alloc(256 * 64 * 4);
    float* fc1WT  = (float*)alloc(128 * 128 * 4);
    float* qstar  = (float*)alloc((size_t)NG_ * 128 * 4);

    k_init<<<(NN_ + NN_ * 64 + 255) / 256, 256, 0, stream>>>(deg, aggb);
    k_lin0<<<NN_ * 64 / 256, 256, 0, stream>>>(x, lin0W, lin0b, nodeA);
    k_cnt<<<NE_ / 256, 256, 0, stream>>>(dst, deg);
    k_scanA<<<NN_ / 256, 256, 0, stream>>>(deg, offs, bsum);
    k_scanC<<<NN_ / 256, 256, 0, stream>>>(bsum, offs, head);
    k_scatter<<<NE_ / 256, 256, 0, stream>>>(dst, head, perm);
    k_gbnd<<<NN_ / 256, 256, 0, stream>>>(batch, gb);
    k_tw<<<256, 256, 0, stream>>>(lWih, lWhh, WihT2, WhhT2, fc1W, fc1WT);
    k_wfrag<<<112, 256, 0, stream>>>(gWih, gWhh, rootW, HHh, HHl, IHh, IHl);
    k_bhat3<<<524288 / 256, 256, 0, stream>>>(e2W, Bhat3);
    k_he<<<NE_ / 16, 256, 0, stream>>>(ea, e1W, e1b, perm, Hhat);   // sorted edge order

    float* curF = nodeA; float* nxtF = nodeB;
    for (int it = 0; it < 3; it++) {
        k_convr<<<NE_ / 64, 256, 0, stream>>>(curF, Hhat, Bhat3, e2b, src, dst, perm, aggb);
        k_mgru<<<NN_ / 64, 256, 0, stream>>>(aggb, offs, curF, HHh, HHl, IHh, IHl,
                                             convb, gbih, gbhh, nxtF);
        float* tf = curF; curF = nxtF; nxtF = tf;
    }

    k_s2s3<<<NG_, 256, 0, stream>>>(curF, gb, WihT2, WhhT2, lbih, lbhh, qstar);
    k_fc<<<NG_, 128, 0, stream>>>(qstar, fc1WT, fc1b, fc2W, fc2b, (float*)d_out);
}